// Round 4
// baseline (109.367 us; speedup 1.0000x reference)
//
#include <hip/hip_runtime.h>
#include <hip/hip_cooperative_groups.h>

namespace cg = cooperative_groups;

// F1Score (chamfer-distance fscore) for B=2, N=M=8192, D=3, fp32.
// Outputs (flat): fscore[2], precision_1[2], precision_2[2] -> 6 floats.
//
// d^2 < 1e-4 implies |delta| < 0.01 per axis -> 16^3 uniform grid (cell =
// 0.0625) means every qualifying neighbor is within <=2 cells per axis
// (<=8 cells). Buckets store point COORDS (float4) so the search has no
// index indirection. All phases fused into ONE cooperative dispatch:
//   P0 zero counters -> sync -> P1 bin -> sync -> P2 search -> sync -> P3 out.
// Counts are exactly the brute-force counts (identical fp32 distance test,
// provable cell-range margin) -> absmax 0 vs numpy reference.

#define THR 1e-4f
#define RAD 0.0100002f          // covers sqrt(1e-4) + fp slack

constexpr int G1    = 16;
constexpr int NCELL = G1 * G1 * G1;   // 4096
constexpr int CAP   = 24;             // bucket capacity (Poisson lam=2)

// ws layout (ints from base; base is 16B aligned):
//   int   cnt[16];                    // found-counts per combo (4 used)
//   int   cellcnt[4][NCELL];          // per-set bucket counts
//   float4 buckets[4][NCELL][CAP];    // point coords per bucket slot
constexpr int CC_OFF = 16;
constexpr int BK_OFF = 16 + 4 * NCELL;          // byte offset 65600, %16 == 0

// ---------------- shared device helpers ----------------

__device__ __forceinline__ void bin_one(int t, int N,
                                        const float* __restrict__ A1,
                                        const float* __restrict__ A2,
                                        int* __restrict__ cellcnt,
                                        float4* __restrict__ buckets)
{
    int set = t / N;                  // arr*2 + b
    int i   = t - set * N;
    int arr = set >> 1, b = set & 1;
    const float* p = (arr ? A2 : A1) + ((size_t)b * N + i) * 3;
    float x = p[0], y = p[1], z = p[2];
    int cx = min(G1 - 1, max(0, (int)(x * (float)G1)));
    int cy = min(G1 - 1, max(0, (int)(y * (float)G1)));
    int cz = min(G1 - 1, max(0, (int)(z * (float)G1)));
    int cell = (cz * G1 + cy) * G1 + cx;
    int slot = atomicAdd(&cellcnt[set * NCELL + cell], 1);
    if (slot < CAP)
        buckets[((size_t)set * NCELL + cell) * CAP + slot] =
            make_float4(x, y, z, 0.0f);
}

__device__ __forceinline__ bool search_one(int t, int N,
                                           const float* __restrict__ A1,
                                           const float* __restrict__ A2,
                                           const int* __restrict__ cellcnt,
                                           const float4* __restrict__ buckets,
                                           int& combo_out)
{
    int combo = t / N;                // dir*2 + b
    int i     = t - combo * N;
    combo_out = combo;
    int dir = combo >> 1, b = combo & 1;
    const float* X = dir ? A2 : A1;
    int yset = (dir ? 0 : 2) + b;     // set index of the Y array

    const float* xp = X + ((size_t)b * N + i) * 3;
    float x0 = xp[0], x1 = xp[1], x2 = xp[2];

    int lo0 = max(0, (int)floorf((x0 - RAD) * (float)G1));
    int hi0 = min(G1 - 1, (int)floorf((x0 + RAD) * (float)G1));
    int lo1 = max(0, (int)floorf((x1 - RAD) * (float)G1));
    int hi1 = min(G1 - 1, (int)floorf((x1 + RAD) * (float)G1));
    int lo2 = max(0, (int)floorf((x2 - RAD) * (float)G1));
    int hi2 = min(G1 - 1, (int)floorf((x2 + RAD) * (float)G1));

    const int*    cc = cellcnt + yset * NCELL;
    const float4* bk = buckets + (size_t)yset * NCELL * CAP;

    bool found = false;
#pragma unroll
    for (int k = 0; k < 8; ++k) {     // static 2x2x2 cell combos, dup-masked
        int cx = (k & 1) ? hi0 : lo0;
        int cy = (k & 2) ? hi1 : lo1;
        int cz = (k & 4) ? hi2 : lo2;
        bool dup = ((k & 1) && hi0 == lo0) ||
                   ((k & 2) && hi1 == lo1) ||
                   ((k & 4) && hi2 == lo2);
        int cell = (cz * G1 + cy) * G1 + cx;
        int c = dup ? 0 : min(cc[cell], CAP);
        const float4* bp = bk + (size_t)cell * CAP;
        for (int j = 0; j < c; ++j) {
            float4 yq = bp[j];        // global_load_dwordx4, L2/L3-hot
            float dx = x0 - yq.x;
            float dy = x1 - yq.y;
            float dz = x2 - yq.z;
            float d  = dx * dx + dy * dy + dz * dz;
            found = found || (d < THR);
        }
    }
    return found;
}

__device__ __forceinline__ void finalize_out(const int* __restrict__ cnt,
                                             float* __restrict__ out, int N)
{
    for (int b = 0; b < 2; ++b) {
        float p1 = (float)cnt[b]     / (float)N;   // dir0: A1 -> A2
        float p2 = (float)cnt[2 + b] / (float)N;   // dir1: A2 -> A1
        float dn = p1 + p2;
        out[b]     = (dn > 0.0f) ? (2.0f * p1 * p2 / dn) : 0.0f;
        out[2 + b] = p1;
        out[4 + b] = p2;
    }
}

// ---------------- fused cooperative kernel ----------------

__global__ void __launch_bounds__(128)
fused_kernel(const float* __restrict__ A1, const float* __restrict__ A2,
             int N, int* __restrict__ ws, float* __restrict__ out)
{
    cg::grid_group grid = cg::this_grid();
    int*    cnt     = ws;
    int*    cellcnt = ws + CC_OFF;
    float4* buckets = (float4*)(ws + BK_OFF);

    const int tid   = (int)(blockIdx.x * blockDim.x + threadIdx.x);
    const int nthr  = (int)(gridDim.x * blockDim.x);
    const int total = 4 * N;

    // P0: zero cnt + cellcnt (buckets need no init: only written slots read)
    for (int i = tid; i < BK_OFF; i += nthr) ws[i] = 0;
    grid.sync();

    // P1: bin all 4 point-sets
    for (int t = tid; t < total; t += nthr)
        bin_one(t, N, A1, A2, cellcnt, buckets);
    grid.sync();

    // P2: search (combo is wave-uniform: N%64==0, t block-consecutive)
    for (int t = tid; t < total; t += nthr) {
        int combo;
        bool found = search_one(t, N, A1, A2, cellcnt, buckets, combo);
        unsigned long long msk = __ballot(found);
        if ((threadIdx.x & 63) == 0 && msk)
            atomicAdd(&cnt[combo], __popcll(msk));
    }
    grid.sync();

    // P3: finalize
    if (tid == 0) finalize_out(cnt, out, N);
}

// ---------------- non-cooperative fallback (round-3 pipeline) ----------------

__global__ void __launch_bounds__(256)
bin_kernel(const float* __restrict__ A1, const float* __restrict__ A2,
           int N, int* __restrict__ cellcnt, float4* __restrict__ buckets)
{
    int t = blockIdx.x * 256 + (int)threadIdx.x;
    if (t < 4 * N) bin_one(t, N, A1, A2, cellcnt, buckets);
}

__global__ void __launch_bounds__(128)
search_kernel(const float* __restrict__ A1, const float* __restrict__ A2,
              int N, const int* __restrict__ cellcnt,
              const float4* __restrict__ buckets, int* __restrict__ cnt)
{
    int t = blockIdx.x * 128 + (int)threadIdx.x;
    int combo;
    bool found = (t < 4 * N) && search_one(t, N, A1, A2, cellcnt, buckets, combo);
    unsigned long long msk = __ballot(found);
    if ((threadIdx.x & 63) == 0 && msk)
        atomicAdd(&cnt[t / N], __popcll(msk));
}

__global__ void finalize_kernel(const int* __restrict__ cnt,
                                float* __restrict__ out, int N)
{
    if (threadIdx.x == 0 && blockIdx.x == 0) finalize_out(cnt, out, N);
}

// ---------------- launch ----------------

extern "C" void kernel_launch(void* const* d_in, const int* in_sizes, int n_in,
                              void* d_out, int out_size, void* d_ws, size_t ws_size,
                              hipStream_t stream)
{
    const float* A1 = (const float*)d_in[0];
    const float* A2 = (const float*)d_in[1];
    float* out = (float*)d_out;

    const int B = 2, D = 3;
    const int N = in_sizes[0] / (B * D);   // 8192 (N == M)

    int*    ws_i    = (int*)d_ws;
    int*    cellcnt = ws_i + CC_OFF;
    float4* buckets = (float4*)(ws_i + BK_OFF);
    int*    cnt     = ws_i;

    const size_t needBytes =
        (size_t)BK_OFF * 4 + (size_t)4 * NCELL * CAP * sizeof(float4);

    int dev = 0, coop = 0;
    hipGetDevice(&dev);
    hipDeviceGetAttribute(&coop, hipDeviceAttributeCooperativeLaunch, dev);

    if (coop && (N % 64) == 0 && ws_size >= needBytes) {
        void* args[] = {(void*)&A1, (void*)&A2, (void*)&N,
                        (void*)&ws_i, (void*)&out};
        hipLaunchCooperativeKernel(reinterpret_cast<void*>(fused_kernel),
                                   dim3(256), dim3(128), args, 0, stream);
    } else {
        // proven 4-dispatch bucket pipeline
        hipMemsetAsync(d_ws, 0, (size_t)BK_OFF * 4, stream);
        bin_kernel<<<(4 * N + 255) / 256, 256, 0, stream>>>(A1, A2, N,
                                                            cellcnt, buckets);
        search_kernel<<<(4 * N + 127) / 128, 128, 0, stream>>>(A1, A2, N,
                                                               cellcnt, buckets, cnt);
        finalize_kernel<<<1, 64, 0, stream>>>(cnt, out, N);
    }
}

// Round 5
// 37.399 us; speedup vs baseline: 2.9243x; 2.9243x over previous
//
#include <hip/hip_runtime.h>

// F1Score (chamfer-distance fscore) for B=2, N=M=8192, D=3, fp32.
// Outputs (flat): fscore[2], precision_1[2], precision_2[2] -> 6 floats.
//
// d^2 < 1e-4 implies |delta| < 0.01 per axis -> 16^3 uniform grid (cell =
// 0.0625): every qualifying neighbor lies within <=2 cells per axis
// (<=8 cells). Buckets store point COORDS (float4): search has no index
// indirection. Pipeline: memset (zero counters) -> fused kernel
// {bin -> hand-rolled agent-scope grid barrier -> search -> ticket finalize}.
// Counts are exactly the brute-force counts (identical fp32 distance test,
// provable cell-range margin) -> absmax 0 vs numpy reference.
//
// NOTE (learned round 4): cg::grid.sync() costs ~30us each on MI355X
// (system-scope L2 flush). The hand-rolled barrier below uses agent-scope
// fences only; all cross-block data flows through it or through atomics.

#define THR 1e-4f
#define RAD 0.0100002f          // covers sqrt(1e-4) + fp slack

constexpr int G1    = 16;
constexpr int NCELL = G1 * G1 * G1;   // 4096
constexpr int CAP   = 24;             // bucket capacity (Poisson lam=2, P(>24)~1e-15)

constexpr int NBLK = 128;             // fused grid: 128 blocks x 256 thr = 32768 = 4*N
constexpr int TPB  = 256;

// ws layout (ints from base):
//   [0..1]   barrier counters (bar_bin, bar_fin)
//   [4..7]   cnt[combo]  (dir*2+b)
//   [16..16+4*NCELL)  cellcnt[4][NCELL]
//   then     float4 buckets[4][NCELL][CAP]   (16B-aligned: 65600 % 16 == 0)
constexpr int CNT_OFF = 4;
constexpr int CC_OFF  = 16;
constexpr int BK_OFF  = 16 + 4 * NCELL;

// ---------------- shared device helpers ----------------

__device__ __forceinline__ void bin_one(int t, int N,
                                        const float* __restrict__ A1,
                                        const float* __restrict__ A2,
                                        int* __restrict__ cellcnt,
                                        float4* __restrict__ buckets)
{
    int set = t / N;                  // arr*2 + b
    int i   = t - set * N;
    int arr = set >> 1, b = set & 1;
    const float* p = (arr ? A2 : A1) + ((size_t)b * N + i) * 3;
    float x = p[0], y = p[1], z = p[2];
    int cx = min(G1 - 1, max(0, (int)(x * (float)G1)));
    int cy = min(G1 - 1, max(0, (int)(y * (float)G1)));
    int cz = min(G1 - 1, max(0, (int)(z * (float)G1)));
    int cell = (cz * G1 + cy) * G1 + cx;
    int slot = atomicAdd(&cellcnt[set * NCELL + cell], 1);
    if (slot < CAP)
        buckets[((size_t)set * NCELL + cell) * CAP + slot] =
            make_float4(x, y, z, 0.0f);
}

__device__ __forceinline__ bool search_one(int t, int N,
                                           const float* __restrict__ A1,
                                           const float* __restrict__ A2,
                                           const int* __restrict__ cellcnt,
                                           const float4* __restrict__ buckets,
                                           int& combo_out)
{
    int combo = t / N;                // dir*2 + b
    int i     = t - combo * N;
    combo_out = combo;
    int dir = combo >> 1, b = combo & 1;
    const float* X = dir ? A2 : A1;
    int yset = (dir ? 0 : 2) + b;     // set index of the Y array

    const float* xp = X + ((size_t)b * N + i) * 3;
    float x0 = xp[0], x1 = xp[1], x2 = xp[2];

    int lo0 = max(0, (int)floorf((x0 - RAD) * (float)G1));
    int hi0 = min(G1 - 1, (int)floorf((x0 + RAD) * (float)G1));
    int lo1 = max(0, (int)floorf((x1 - RAD) * (float)G1));
    int hi1 = min(G1 - 1, (int)floorf((x1 + RAD) * (float)G1));
    int lo2 = max(0, (int)floorf((x2 - RAD) * (float)G1));
    int hi2 = min(G1 - 1, (int)floorf((x2 + RAD) * (float)G1));

    const int*    cc = cellcnt + yset * NCELL;
    const float4* bk = buckets + (size_t)yset * NCELL * CAP;

    bool found = false;
#pragma unroll
    for (int k = 0; k < 8; ++k) {     // static 2x2x2 cell combos, dup-masked
        int cx = (k & 1) ? hi0 : lo0;
        int cy = (k & 2) ? hi1 : lo1;
        int cz = (k & 4) ? hi2 : lo2;
        bool dup = ((k & 1) && hi0 == lo0) ||
                   ((k & 2) && hi1 == lo1) ||
                   ((k & 4) && hi2 == lo2);
        int cell = (cz * G1 + cy) * G1 + cx;
        int c = dup ? 0 : min(cc[cell], CAP);
        const float4* bp = bk + (size_t)cell * CAP;
        for (int j = 0; j < c; ++j) {
            float4 yq = bp[j];
            float dx = x0 - yq.x;
            float dy = x1 - yq.y;
            float dz = x2 - yq.z;
            float d  = dx * dx + dy * dy + dz * dz;
            found = found || (d < THR);
        }
    }
    return found;
}

__device__ __forceinline__ void finalize_out(const int* __restrict__ cnt,
                                             float* __restrict__ out, int N)
{
    for (int b = 0; b < 2; ++b) {
        float p1 = (float)cnt[b]     / (float)N;   // dir0: A1 -> A2
        float p2 = (float)cnt[2 + b] / (float)N;   // dir1: A2 -> A1
        float dn = p1 + p2;
        out[b]     = (dn > 0.0f) ? (2.0f * p1 * p2 / dn) : 0.0f;
        out[2 + b] = p1;
        out[4 + b] = p2;
    }
}

// ---------------- fused kernel with hand-rolled agent-scope barrier --------

__global__ void __launch_bounds__(TPB)
fused_kernel(const float* __restrict__ A1, const float* __restrict__ A2,
             int N, int* __restrict__ ws, float* __restrict__ out)
{
    int*    bar     = ws;             // [0] bin-barrier, [1] finalize ticket
    int*    cnt     = ws + CNT_OFF;
    int*    cellcnt = ws + CC_OFF;
    float4* buckets = (float4*)(ws + BK_OFF);

    const int tid   = (int)(blockIdx.x * blockDim.x + threadIdx.x);
    const int nthr  = NBLK * TPB;
    const int total = 4 * N;

    // P1: bin all 4 point-sets (cellcnt/bar pre-zeroed by the memset dispatch)
    for (int t = tid; t < total; t += nthr)
        bin_one(t, N, A1, A2, cellcnt, buckets);

    // grid barrier: agent-scope release -> arrive -> spin -> acquire
    __syncthreads();
    if (threadIdx.x == 0) {
        __builtin_amdgcn_fence(__ATOMIC_RELEASE, "agent");   // wb local L2
        __hip_atomic_fetch_add(&bar[0], 1, __ATOMIC_RELAXED,
                               __HIP_MEMORY_SCOPE_AGENT);
        while (__hip_atomic_load(&bar[0], __ATOMIC_RELAXED,
                                 __HIP_MEMORY_SCOPE_AGENT) < NBLK)
            __builtin_amdgcn_s_sleep(2);
        __builtin_amdgcn_fence(__ATOMIC_ACQUIRE, "agent");   // inv local L2
    }
    __syncthreads();

    // P2: search (combo wave-uniform: N%64==0, t consecutive per wave)
    for (int t = tid; t < total; t += nthr) {
        int combo;
        bool found = search_one(t, N, A1, A2, cellcnt, buckets, combo);
        unsigned long long msk = __ballot(found);
        if ((threadIdx.x & 63) == 0 && msk)
            atomicAdd(&cnt[combo], __popcll(msk));
    }

    // P3: ticket finalize — last block to arrive writes the 6 outputs
    __syncthreads();
    if (threadIdx.x == 0) {
        __builtin_amdgcn_fence(__ATOMIC_RELEASE, "agent");
        int tkt = __hip_atomic_fetch_add(&bar[1], 1, __ATOMIC_RELAXED,
                                         __HIP_MEMORY_SCOPE_AGENT);
        if (tkt == NBLK - 1) {
            __builtin_amdgcn_fence(__ATOMIC_ACQUIRE, "agent");
            finalize_out(cnt, out, N);
        }
    }
}

// ---------------- proven 4-dispatch fallback (round 3) ----------------

__global__ void __launch_bounds__(256)
bin_kernel(const float* __restrict__ A1, const float* __restrict__ A2,
           int N, int* __restrict__ cellcnt, float4* __restrict__ buckets)
{
    int t = blockIdx.x * 256 + (int)threadIdx.x;
    if (t < 4 * N) bin_one(t, N, A1, A2, cellcnt, buckets);
}

__global__ void __launch_bounds__(128)
search_kernel(const float* __restrict__ A1, const float* __restrict__ A2,
              int N, const int* __restrict__ cellcnt,
              const float4* __restrict__ buckets, int* __restrict__ cnt)
{
    int t = blockIdx.x * 128 + (int)threadIdx.x;
    int combo;
    bool found = (t < 4 * N) && search_one(t, N, A1, A2, cellcnt, buckets, combo);
    unsigned long long msk = __ballot(found);
    if ((threadIdx.x & 63) == 0 && msk)
        atomicAdd(&cnt[t / N], __popcll(msk));
}

__global__ void finalize_kernel(const int* __restrict__ cnt,
                                float* __restrict__ out, int N)
{
    if (threadIdx.x == 0 && blockIdx.x == 0) finalize_out(cnt, out, N);
}

// ---------------- launch ----------------

extern "C" void kernel_launch(void* const* d_in, const int* in_sizes, int n_in,
                              void* d_out, int out_size, void* d_ws, size_t ws_size,
                              hipStream_t stream)
{
    const float* A1 = (const float*)d_in[0];
    const float* A2 = (const float*)d_in[1];
    float* out = (float*)d_out;

    const int B = 2, D = 3;
    const int N = in_sizes[0] / (B * D);   // 8192 (N == M)

    int*    ws_i    = (int*)d_ws;
    int*    cellcnt = ws_i + CC_OFF;
    float4* buckets = (float4*)(ws_i + BK_OFF);
    int*    cnt     = ws_i + CNT_OFF;

    const size_t needBytes =
        (size_t)BK_OFF * 4 + (size_t)4 * NCELL * CAP * sizeof(float4);

    // zero bar + cnt + cellcnt (buckets need no init: only written slots read)
    hipMemsetAsync(d_ws, 0, (size_t)BK_OFF * 4, stream);

    if (4 * N == NBLK * TPB && (N % 64) == 0 && ws_size >= needBytes) {
        fused_kernel<<<NBLK, TPB, 0, stream>>>(A1, A2, N, ws_i, out);
    } else {
        bin_kernel<<<(4 * N + 255) / 256, 256, 0, stream>>>(A1, A2, N,
                                                            cellcnt, buckets);
        search_kernel<<<(4 * N + 127) / 128, 128, 0, stream>>>(A1, A2, N,
                                                               cellcnt, buckets, cnt);
        finalize_kernel<<<1, 64, 0, stream>>>(cnt, out, N);
    }
}